// Round 9
// baseline (171.967 us; speedup 1.0000x reference)
//
#include <hip/hip_runtime.h>

// LandmarkLoss, round 9. B=4, N=200000, K=64.
// The R1-R8 ghost (wall-minus-busy ~20us) tracks the per-iteration in-loop
// LDS read. This round makes the K-loop PURE VALU:
//  * Setup kernel pre-transforms targets (-2t, |t|^2+WBIAS) into ws.
//  * 256-thr block = 4 waves sharing one 256-pt chunk; wave w owns targets
//    [16w,16w+16). Target reads are wave-uniform s_load_dwordx4 (index forced
//    uniform via readfirstlane) -- hoisted, zero in-loop memory ops.
//  * Per-target g2p min accumulates in a statically-indexed register array
//    dlreg[16]; post-loop 6-step shfl_xor butterfly reduces across lanes;
//    lane 0 fires 16 fire-and-forget global atomicMax (encode ~bits).
//  * 4-way top-2 key merge via one LDS publish + single barrier; wave 3
//    runs the point epilogue (companions from tgtLDS) + 3 atomicAdds.
//  * Carried: key-packing, packed-fp32 dot pairs, x16 replicated sums/g2p,
//    f0 dummy trick, tiny finalize dispatch.

constexpr int KT = 64;
constexpr int P  = 4;
constexpr int NREP = 16;
constexpr float DIST_THRESH = 0.1f;
constexpr float W_DIST    = 0.05f;
constexpr float W_CHAMFER = 0.05f;
constexpr float W_SEP     = 0.0005f;
constexpr float PT_SENT = -1e18f;  // dummy-point sentinel (tail lanes)
constexpr float TG_SENT = -1e18f;  // invalid-target sentinel
constexpr float BIGF  = 3.0e38f;
constexpr float WBIAS = 16.0f;     // |t|^2 + WBIAS in T.w keeps valid keys > 0

typedef float f2 __attribute__((ext_vector_type(2)));

__device__ __forceinline__ unsigned umin_(unsigned a, unsigned b) { return a < b ? a : b; }
__device__ __forceinline__ unsigned umax_(unsigned a, unsigned b) { return a > b ? a : b; }

__device__ __forceinline__ f2 pk_fma(f2 a, f2 b, f2 c) {
#if __has_builtin(__builtin_elementwise_fma)
    return __builtin_elementwise_fma(a, b, c);
#else
    f2 r; r.x = fmaf(a.x, b.x, c.x); r.y = fmaf(a.y, b.y, c.y); return r;
#endif
}

// ws layout: [0,16384) g2p replicas rep*256+b*64+k (encode ~bits(g), init 0);
//            [16384,17408) sums replicas rep*16 + c*4 + b (float, init 0);
//            [17408,21504) transformed targets: b*64+k float4

__global__ void landmark_setup(const float* __restrict__ tC, const int* __restrict__ tF,
                               const int* __restrict__ classes, int n_classes,
                               float4* __restrict__ tws)
{
    const int t = threadIdx.x;        // 256
    const int b = t >> 6, k = t & 63;
    int f = tF[b * KT + k];
    bool valid = false;
    for (int c = 0; c < n_classes; ++c) valid = valid || (f == classes[c]);
    float x = TG_SENT, y = TG_SENT, z = TG_SENT;
    if (valid) {
        x = tC[(b * KT + k) * 3 + 0];
        y = tC[(b * KT + k) * 3 + 1];
        z = tC[(b * KT + k) * 3 + 2];
    }
    tws[b * KT + k] = make_float4(-2.f * x, -2.f * y, -2.f * z,
                                  x * x + y * y + z * z + WBIAS);
}

__global__ __launch_bounds__(256, 4)
void landmark_main(const float* __restrict__ C, const float* __restrict__ F,
                   const float4* __restrict__ tws, int N,
                   unsigned int* __restrict__ g2p_rep, float* __restrict__ sums_rep)
{
    __shared__ float4 tgtLDS[KT];      // full target list for epilogue lookups
    __shared__ uint4  pubK1[3][64];    // waves 0..2 -> wave 3 merge buffers
    __shared__ uint4  pubK2[3][64];
    __shared__ float4 pubLM[3][64];

    const int tid   = threadIdx.x;
    const int lane  = tid & 63;
    const int wib   = tid >> 6;
    const int ksplit = __builtin_amdgcn_readfirstlane(wib);  // force uniform
    const int blk   = blockIdx.x;
    const int b     = blk & 3;
    const int chunk = blk >> 2;
    const int rep   = chunk & (NREP - 1);

    if (wib == 0) tgtLDS[lane] = tws[b * KT + lane];

    const float*  Cb = C + (size_t)b * N * 3;
    const float4* Fb = (const float4*)(F + (size_t)b * N * 4);
    const int base = chunk * (64 * P);

    // ---- stage this chunk's 256 points (all 4 waves load the same points) ----
    f2 pcx[P], pcy[P], pcz[P];         // (raw coord, offset coord) packed pairs
    float ccm[P], f0[P];
    #pragma unroll
    for (int p = 0; p < P; ++p) {
        int n = base + p * 64 + lane;
        bool v = (n < N);
        int ni = v ? n : 0;
        float4 f4 = Fb[ni];
        float X = Cb[3 * ni + 0], Y = Cb[3 * ni + 1], Z = Cb[3 * ni + 2];
        // dummy points: coords -> sentinel; f0 -> 0.2 so dist term cancels.
        f0[p] = v ? f4.x : 2.0f * DIST_THRESH;
        if (!v) { X = PT_SENT; Y = PT_SENT; Z = PT_SENT; f4.y = f4.z = f4.w = 0.f; }
        float cxv = X + f4.y, cyv = Y + f4.z, czv = Z + f4.w;
        pcx[p] = (f2){X, cxv};
        pcy[p] = (f2){Y, cyv};
        pcz[p] = (f2){Z, czv};
        ccm[p] = fmaf(czv, czv, fmaf(cyv, cyv, cxv * cxv)) - WBIAS;
    }

    // keyf = T.w - 2 p.t (= true pd2 - |p|^2 + WBIAS, > 0 for valid pairs)
    unsigned k1[P], k2[P];
    float lmin[P], dlreg[16];
    #pragma unroll
    for (int p = 0; p < P; ++p) { k1[p] = 0xFFFFFFFFu; k2[p] = 0xFFFFFFFFu; lmin[p] = BIGF; }

    const float4* tb = tws + b * KT + ksplit * 16;   // this wave's 16 targets

    #pragma unroll
    for (int i = 0; i < 16; ++i) {
        const float4 T = tb[i];                      // uniform addr -> s_load
        const unsigned tk = (unsigned)(ksplit * 16 + i);
        const f2 Tx = {T.x, T.x}, Ty = {T.y, T.y}, Tz = {T.z, T.z}, Tw = {T.w, T.w};
        float av[P];
        #pragma unroll
        for (int p = 0; p < P; ++p) {
            f2 w = pk_fma(pcx[p], Tx, pk_fma(pcy[p], Ty, pk_fma(pcz[p], Tz, Tw)));
            unsigned key = (__float_as_uint(w.x) & 0xFFFFFFC0u) | tk;
            unsigned hi = umax_(k1[p], key);
            k1[p] = umin_(k1[p], key);
            k2[p] = umin_(k2[p], hi);
            lmin[p] = fminf(lmin[p], w.y);
            av[p] = w.y + ccm[p];                    // true ld2 for cross-p compare
        }
        dlreg[i] = fmaxf(fminf(fminf(av[0], av[1]), fminf(av[2], av[3])), 0.f);
    }

    // ---- butterfly: per-target min across all 64 lanes, in registers ----
    #pragma unroll
    for (int d = 1; d < 64; d <<= 1) {
        #pragma unroll
        for (int i = 0; i < 16; ++i)
            dlreg[i] = fminf(dlreg[i], __shfl_xor(dlreg[i], d, 64));
    }
    if (lane == 0) {
        unsigned gb = rep * 256 + b * 64 + ksplit * 16;
        #pragma unroll
        for (int i = 0; i < 16; ++i)
            // ~bits monotone decreasing for g>=0: atomicMax == min; init 0 loses.
            atomicMax(&g2p_rep[gb + i], ~__float_as_uint(dlreg[i]));
    }

    // ---- waves 0..2 publish per-point top-2 state; wave 3 merges ----
    if (wib < 3) {
        pubK1[wib][lane] = make_uint4(k1[0], k1[1], k1[2], k1[3]);
        pubK2[wib][lane] = make_uint4(k2[0], k2[1], k2[2], k2[3]);
        pubLM[wib][lane] = make_float4(lmin[0], lmin[1], lmin[2], lmin[3]);
    }
    __syncthreads();

    if (wib == 3) {
        float dist_acc = 0.f, p2g_acc = 0.f, sep_acc = 0.f;
        uint4 K1s[3], K2s[3]; float4 LMs[3];
        #pragma unroll
        for (int w = 0; w < 3; ++w) {
            K1s[w] = pubK1[w][lane]; K2s[w] = pubK2[w][lane]; LMs[w] = pubLM[w][lane];
        }
        #pragma unroll
        for (int p = 0; p < P; ++p) {
            unsigned m1 = k1[p], m2 = k2[p];
            float lm = lmin[p];
            #pragma unroll
            for (int w = 0; w < 3; ++w) {
                unsigned o1 = (p == 0) ? K1s[w].x : (p == 1) ? K1s[w].y : (p == 2) ? K1s[w].z : K1s[w].w;
                unsigned o2 = (p == 0) ? K2s[w].x : (p == 1) ? K2s[w].y : (p == 2) ? K2s[w].z : K2s[w].w;
                float    ol = (p == 0) ? LMs[w].x : (p == 1) ? LMs[w].y : (p == 2) ? LMs[w].z : LMs[w].w;
                m2 = umin_(umax_(m1, o1), umin_(m2, o2));
                m1 = umin_(m1, o1);
                lm = fminf(lm, ol);
            }
            float X = pcx[p].x, Y = pcy[p].x, Z = pcz[p].x;
            float ppm = fmaf(Z, Z, fmaf(Y, Y, X * X)) - WBIAS;
            float keyf1 = __uint_as_float(m1 & 0xFFFFFFC0u);
            float mind = sqrtf(fmaxf(keyf1 + ppm, 0.f));
            bool pm = mind < DIST_THRESH;            // false for dummy (ppm huge)
            float tgtv = fminf(mind, 2.0f * DIST_THRESH);
            float diff = f0[p] - tgtv;
            float ad = fabsf(diff);
            dist_acc += (ad < 1.0f) ? 0.5f * diff * diff : (ad - 0.5f);
            if (pm) {
                p2g_acc += fmaxf(lm + ccm[p], 0.f);
                int i1 = (int)(m1 & 63u), i2 = (int)(m2 & 63u);
                float4 T1 = tgtLDS[i1], T2 = tgtLDS[i2];
                float cxv = pcx[p].y, cyv = pcy[p].y, czv = pcz[p].y;
                float l1sq = fmaf(cxv, T1.x, fmaf(cyv, T1.y, fmaf(czv, T1.z, T1.w))) + ccm[p];
                float l2sq = fmaf(cxv, T2.x, fmaf(cyv, T2.y, fmaf(czv, T2.z, T2.w))) + ccm[p];
                sep_acc += sqrtf(fmaxf(l1sq, 0.f) / fmaxf(l2sq, 1e-30f));
            }
        }

        float v0 = dist_acc, v1 = p2g_acc, v2 = sep_acc;
        #pragma unroll
        for (int o = 32; o > 0; o >>= 1) {
            v0 += __shfl_down(v0, o, 64);
            v1 += __shfl_down(v1, o, 64);
            v2 += __shfl_down(v2, o, 64);
        }
        if (lane == 0) {
            float* sb = sums_rep + rep * 16 + b;
            atomicAdd(sb + 0, v0);
            atomicAdd(sb + 4, v1);
            atomicAdd(sb + 8, v2);
        }
    }
}

__global__ void landmark_finalize(const int* __restrict__ tF, const int* __restrict__ classes,
                                  int n_classes, const unsigned int* __restrict__ g2p_rep,
                                  const float* __restrict__ sums_rep, float* __restrict__ out)
{
    __shared__ float lossb[4];
    const int tid = threadIdx.x;          // 256 threads
    const int b = tid >> 6, k = tid & 63;

    int f = tF[b * KT + k];
    bool valid = false;
    for (int c = 0; c < n_classes; ++c) valid = valid || (f == classes[c]);

    unsigned enc = 0;
    for (int r = 0; r < NREP; ++r) enc = umax_(enc, g2p_rep[r * 256 + b * 64 + k]);
    float g  = valid ? __uint_as_float(~enc) : 0.f;
    float nv = valid ? 1.f : 0.f;

    #pragma unroll
    for (int o = 32; o > 0; o >>= 1) {
        g  += __shfl_down(g, o, 64);
        nv += __shfl_down(nv, o, 64);
    }
    if (k == 0) {
        float sd = 0.f, sp = 0.f, ss = 0.f;
        for (int r = 0; r < NREP; ++r) {
            sd += sums_rep[r * 16 + 0 + b];
            sp += sums_rep[r * 16 + 4 + b];
            ss += sums_rep[r * 16 + 8 + b];
        }
        float sep = (nv >= 2.f) ? ss : 0.f;
        lossb[b] = W_DIST * sd + W_CHAMFER * (sp + g) + W_SEP * sep;
    }
    __syncthreads();
    if (tid == 0)
        out[0] = (lossb[0] + lossb[1] + lossb[2] + lossb[3]) * 0.25f;
}

extern "C" void kernel_launch(void* const* d_in, const int* in_sizes, int n_in,
                              void* d_out, int out_size, void* d_ws, size_t ws_size,
                              hipStream_t stream)
{
    const float* C       = (const float*)d_in[0];   // (B,N,3)
    const float* F       = (const float*)d_in[1];   // (B,N,4)
    const float* tC      = (const float*)d_in[2];   // (B,K,3)
    const int*   tF      = (const int*)d_in[3];     // (B,K)
    const int*   classes = (const int*)d_in[4];     // (6,)
    const int n_classes = in_sizes[4];
    const int B = 4;
    const int N = in_sizes[0] / (3 * B);            // 200000

    unsigned int* g2p_rep  = (unsigned int*)d_ws;
    float*        sums_rep = (float*)((char*)d_ws + NREP * 256 * 4);
    float4*       tws      = (float4*)((char*)d_ws + NREP * 256 * 4 + NREP * 16 * 4);

    hipMemsetAsync(d_ws, 0, NREP * 256 * 4 + NREP * 16 * 4, stream);

    landmark_setup<<<1, 256, 0, stream>>>(tC, tF, classes, n_classes, tws);

    const int cpb = (N + 64 * P - 1) / (64 * P);    // 782 chunks per batch
    landmark_main<<<cpb * 4, 256, 0, stream>>>(C, F, tws, N, g2p_rep, sums_rep);
    landmark_finalize<<<1, 256, 0, stream>>>(tF, classes, n_classes, g2p_rep,
                                             sums_rep, (float*)d_out);
}

// Round 10
// 105.429 us; speedup vs baseline: 1.6311x; 1.6311x over previous
//
#include <hip/hip_runtime.h>

// LandmarkLoss, round 10. B=4, N=200000, K=64.
// R9 post-mortem: register-resident per-target accumulators spilled to
// scratch (FETCH 114MB / WRITE 235MB of spill traffic, VGPR capped at 64).
// Revert to the R7 structure (best, ~32us stack) with the K-split folded
// into LANE HALVES of one wave instead of two waves:
//  * lanes 0-31 process targets [0,32), lanes 32-63 process [32,64);
//    both halves hold the same 32*P points (same redundancy as R7).
//  * in-loop T read: tgt[lane ^ i] -- one v_xor of address math, and all
//    64 lanes hit 64 DISTINCT g2pLDS words: the fire-and-forget ds_min is
//    same-address-conflict-free (R7 had lanes l,l+32 colliding every iter).
//  * cross-half top-2 merge: 3 shfl_xor(32) per point ONCE per chunk --
//    kills R7's LDS publish buffers, their traffic, and the idle wave-A
//    during wave-B's epilogue. Epilogue parallelism doubles (P/2 per half).
//  * wave count stays 6252 (R7's sweet spot: 6.1 waves/SIMD resident).
//  * carried: key-packing top-2, packed-fp32 dot pairs, f0 dummy trick,
//    x16 replicated global atomics, tiny finalize dispatch.

constexpr int KT = 64;
constexpr int P  = 4;              // points per lane; 32*P = 128 points per wave
constexpr int NREP = 16;
constexpr float DIST_THRESH = 0.1f;
constexpr float W_DIST    = 0.05f;
constexpr float W_CHAMFER = 0.05f;
constexpr float W_SEP     = 0.0005f;
constexpr float PT_SENT = -1e18f;  // dummy-point sentinel (tail lanes)
constexpr float TG_SENT = -1e18f;  // invalid-target sentinel
constexpr float BIGF  = 3.0e38f;
constexpr float WBIAS = 16.0f;     // |t|^2 + WBIAS in T.w keeps valid keys > 0

typedef float f2 __attribute__((ext_vector_type(2)));

__device__ __forceinline__ unsigned umin_(unsigned a, unsigned b) { return a < b ? a : b; }
__device__ __forceinline__ unsigned umax_(unsigned a, unsigned b) { return a > b ? a : b; }

__device__ __forceinline__ f2 pk_fma(f2 a, f2 b, f2 c) {
#if __has_builtin(__builtin_elementwise_fma)
    return __builtin_elementwise_fma(a, b, c);
#else
    f2 r; r.x = fmaf(a.x, b.x, c.x); r.y = fmaf(a.y, b.y, c.y); return r;
#endif
}

// ws layout: [0,16384) g2p replicas rep*256+b*64+k (encode ~bits(g), init 0);
//            [16384,17408) sums replicas rep*16 + c*4 + b (float, init 0)
__global__ __launch_bounds__(256, 6)
void landmark_main(const float* __restrict__ C, const float* __restrict__ F,
                   const float* __restrict__ tC, const int* __restrict__ tF,
                   const int* __restrict__ classes, int n_classes,
                   int N, int cpb,
                   unsigned int* __restrict__ g2p_rep, float* __restrict__ sums_rep)
{
    __shared__ float4 tgt[KT];         // transformed targets (whole K)
    __shared__ unsigned g2pLDS[KT];    // per-target min bits (float >= 0)
    __shared__ float rs[3][4];         // per-wave partial sums

    const int tid   = threadIdx.x;
    const int lane  = tid & 63;
    const int wib   = tid >> 6;
    const int l31   = lane & 31;
    const int half  = lane >> 5;       // 0: targets [0,32), 1: [32,64)
    const int blk   = blockIdx.x;
    const int b     = blk & 3;
    const int chunk = (blk >> 2) * 4 + wib;
    const int rep   = blk & (NREP - 1);

    // Stage 64 targets: (-2tx,-2ty,-2tz, |t|^2+WBIAS), sentinel if invalid.
    if (tid < KT) {
        int f = tF[b * KT + tid];
        bool valid = false;
        for (int c = 0; c < n_classes; ++c) valid = valid || (f == classes[c]);
        float x = TG_SENT, y = TG_SENT, z = TG_SENT;
        if (valid) {
            x = tC[(b * KT + tid) * 3 + 0];
            y = tC[(b * KT + tid) * 3 + 1];
            z = tC[(b * KT + tid) * 3 + 2];
        }
        tgt[tid] = make_float4(-2.f * x, -2.f * y, -2.f * z,
                               x * x + y * y + z * z + WBIAS);
        g2pLDS[tid] = 0x7F7FFFFFu;     // FLT_MAX bits
    }
    __syncthreads();

    float dist_acc = 0.f, p2g_acc = 0.f, sep_acc = 0.f;

    if (chunk < cpb) {
        const float*  Cb = C + (size_t)b * N * 3;
        const float4* Fb = (const float4*)(F + (size_t)b * N * 4);
        const int base = chunk * (32 * P);

        // ---- stage this chunk's 128 points (both lane-halves load same) ----
        f2 pcx[P], pcy[P], pcz[P];     // (raw coord, offset coord) packed pairs
        float ccm[P], f0[P];
        #pragma unroll
        for (int p = 0; p < P; ++p) {
            int n = base + p * 32 + l31;
            bool v = (n < N);
            int ni = v ? n : 0;
            float4 f4 = Fb[ni];
            float X = Cb[3 * ni + 0], Y = Cb[3 * ni + 1], Z = Cb[3 * ni + 2];
            // dummy points: coords -> sentinel; f0 -> 0.2 so dist term cancels.
            f0[p] = v ? f4.x : 2.0f * DIST_THRESH;
            if (!v) { X = PT_SENT; Y = PT_SENT; Z = PT_SENT; f4.y = f4.z = f4.w = 0.f; }
            float cxv = X + f4.y, cyv = Y + f4.z, czv = Z + f4.w;
            pcx[p] = (f2){X, cxv};
            pcy[p] = (f2){Y, cyv};
            pcz[p] = (f2){Z, czv};
            ccm[p] = fmaf(czv, czv, fmaf(cyv, cyv, cxv * cxv)) - WBIAS;
        }

        // keyf = T.w - 2 p.t (= true pd2 - |p|^2 + WBIAS, > 0 for valid pairs)
        unsigned k1[P], k2[P];
        float lmin[P];
        #pragma unroll
        for (int p = 0; p < P; ++p) { k1[p] = 0xFFFFFFFFu; k2[p] = 0xFFFFFFFFu; lmin[p] = BIGF; }

        #pragma unroll 8
        for (int i = 0; i < 32; ++i) {
            const unsigned tk = (unsigned)(lane ^ i);   // stays within lane's half
            const float4 T = tgt[tk];                   // 64 distinct addresses
            const f2 Tx = {T.x, T.x}, Ty = {T.y, T.y}, Tz = {T.z, T.z}, Tw = {T.w, T.w};
            float av[P];
            #pragma unroll
            for (int p = 0; p < P; ++p) {
                f2 w = pk_fma(pcx[p], Tx, pk_fma(pcy[p], Ty, pk_fma(pcz[p], Tz, Tw)));
                unsigned key = (__float_as_uint(w.x) & 0xFFFFFFC0u) | tk;
                unsigned hi = umax_(k1[p], key);
                k1[p] = umin_(k1[p], key);
                k2[p] = umin_(k2[p], hi);
                lmin[p] = fminf(lmin[p], w.y);
                av[p] = w.y + ccm[p];                   // true ld2 for cross-p compare
            }
            float dl = fmaxf(fminf(fminf(av[0], av[1]), fminf(av[2], av[3])), 0.f);
            atomicMin(&g2pLDS[tk], __float_as_uint(dl));   // ds_min_u32, no return
        }

        // ---- merge target-halves: 3 shfl_xor(32) per point, once per chunk ----
        #pragma unroll
        for (int p = 0; p < P; ++p) {
            unsigned o1 = (unsigned)__shfl_xor((int)k1[p], 32, 64);
            unsigned o2 = (unsigned)__shfl_xor((int)k2[p], 32, 64);
            k2[p] = umin_(umax_(k1[p], o1), umin_(k2[p], o2));
            k1[p] = umin_(k1[p], o1);
            lmin[p] = fminf(lmin[p], __shfl_xor(lmin[p], 32, 64));
        }

        // ---- epilogue: each half handles P/2 points (state is identical) ----
        const int p0 = half * (P / 2);
        #pragma unroll
        for (int pp = 0; pp < P / 2; ++pp) {
            const int p = p0 + pp;
            float X = pcx[p].x, Y = pcy[p].x, Z = pcz[p].x;
            float ppm = fmaf(Z, Z, fmaf(Y, Y, X * X)) - WBIAS;
            float keyf1 = __uint_as_float(k1[p] & 0xFFFFFFC0u);
            float mind = sqrtf(fmaxf(keyf1 + ppm, 0.f));
            bool pm = mind < DIST_THRESH;              // false for dummy (ppm huge)
            float tgtv = fminf(mind, 2.0f * DIST_THRESH);
            float diff = f0[p] - tgtv;
            float ad = fabsf(diff);
            dist_acc += (ad < 1.0f) ? 0.5f * diff * diff : (ad - 0.5f);
            if (pm) {
                p2g_acc += fmaxf(lmin[p] + ccm[p], 0.f);
                int i1 = (int)(k1[p] & 63u), i2 = (int)(k2[p] & 63u);
                float4 T1 = tgt[i1], T2 = tgt[i2];
                float cxv = pcx[p].y, cyv = pcy[p].y, czv = pcz[p].y;
                float l1sq = fmaf(cxv, T1.x, fmaf(cyv, T1.y, fmaf(czv, T1.z, T1.w))) + ccm[p];
                float l2sq = fmaf(cxv, T2.x, fmaf(cyv, T2.y, fmaf(czv, T2.z, T2.w))) + ccm[p];
                sep_acc += sqrtf(fmaxf(l1sq, 0.f) / fmaxf(l2sq, 1e-30f));
            }
        }
    }

    // ---- wave reduce + block combine ----
    float v0 = dist_acc, v1 = p2g_acc, v2 = sep_acc;
    #pragma unroll
    for (int o = 32; o > 0; o >>= 1) {
        v0 += __shfl_down(v0, o, 64);
        v1 += __shfl_down(v1, o, 64);
        v2 += __shfl_down(v2, o, 64);
    }
    if (lane == 0) { rs[0][wib] = v0; rs[1][wib] = v1; rs[2][wib] = v2; }
    __syncthreads();   // also covers all waves' ds_min completion

    if (tid < KT) {
        // g2pLDS holds bits(g), g>=0; ~bits monotone decreasing -> atomicMax == min.
        atomicMax(&g2p_rep[rep * 256 + b * 64 + tid], ~g2pLDS[tid]);
    }
    if (tid < 3) {
        float s = rs[tid][0] + rs[tid][1] + rs[tid][2] + rs[tid][3];
        atomicAdd(&sums_rep[rep * 16 + tid * 4 + b], s);
    }
}

__global__ void landmark_finalize(const int* __restrict__ tF, const int* __restrict__ classes,
                                  int n_classes, const unsigned int* __restrict__ g2p_rep,
                                  const float* __restrict__ sums_rep, float* __restrict__ out)
{
    __shared__ float lossb[4];
    const int tid = threadIdx.x;          // 256 threads
    const int b = tid >> 6, k = tid & 63;

    int f = tF[b * KT + k];
    bool valid = false;
    for (int c = 0; c < n_classes; ++c) valid = valid || (f == classes[c]);

    unsigned enc = 0;
    for (int r = 0; r < NREP; ++r) enc = umax_(enc, g2p_rep[r * 256 + b * 64 + k]);
    float g  = valid ? __uint_as_float(~enc) : 0.f;
    float nv = valid ? 1.f : 0.f;

    #pragma unroll
    for (int o = 32; o > 0; o >>= 1) {
        g  += __shfl_down(g, o, 64);
        nv += __shfl_down(nv, o, 64);
    }
    if (k == 0) {
        float sd = 0.f, sp = 0.f, ss = 0.f;
        for (int r = 0; r < NREP; ++r) {
            sd += sums_rep[r * 16 + 0 + b];
            sp += sums_rep[r * 16 + 4 + b];
            ss += sums_rep[r * 16 + 8 + b];
        }
        float sep = (nv >= 2.f) ? ss : 0.f;
        lossb[b] = W_DIST * sd + W_CHAMFER * (sp + g) + W_SEP * sep;
    }
    __syncthreads();
    if (tid == 0)
        out[0] = (lossb[0] + lossb[1] + lossb[2] + lossb[3]) * 0.25f;
}

extern "C" void kernel_launch(void* const* d_in, const int* in_sizes, int n_in,
                              void* d_out, int out_size, void* d_ws, size_t ws_size,
                              hipStream_t stream)
{
    const float* C       = (const float*)d_in[0];   // (B,N,3)
    const float* F       = (const float*)d_in[1];   // (B,N,4)
    const float* tC      = (const float*)d_in[2];   // (B,K,3)
    const int*   tF      = (const int*)d_in[3];     // (B,K)
    const int*   classes = (const int*)d_in[4];     // (6,)
    const int n_classes = in_sizes[4];
    const int B = 4;
    const int N = in_sizes[0] / (3 * B);            // 200000

    unsigned int* g2p_rep  = (unsigned int*)d_ws;
    float*        sums_rep = (float*)((char*)d_ws + NREP * 256 * 4);

    hipMemsetAsync(d_ws, 0, NREP * 256 * 4 + NREP * 16 * 4, stream);

    const int cpb = (N + 32 * P - 1) / (32 * P);    // 1563 wave-chunks per batch
    const int bpb = (cpb + 3) / 4;                  // 391 blocks per batch
    landmark_main<<<bpb * 4, 256, 0, stream>>>(C, F, tC, tF, classes, n_classes,
                                               N, cpb, g2p_rep, sums_rep);
    landmark_finalize<<<1, 256, 0, stream>>>(tF, classes, n_classes, g2p_rep,
                                             sums_rep, (float*)d_out);
}

// Round 11
// 97.837 us; speedup vs baseline: 1.7577x; 1.0776x over previous
//
#include <hip/hip_runtime.h>

// LandmarkLoss, round 11. B=4, N=200000, K=64.
// Revert to R7 (best: ~32us main stack, 99.3 total) with ONE surgical fix:
// R7's in-loop ds_min had lanes l and l+32 hitting the SAME g2pLDS word every
// iteration (same-address atomics serialize, unlike reads which broadcast).
// Fix: rotation kk = l31 ^ (half<<4) ^ i -- still a per-lane bijection over
// the wave's 32 targets, T-reads stay within the 32-entry half (<=32 distinct
// addresses per ds_read_b128, same bandwidth as R7), but the two lane-halves'
// ds_min addresses are now disjoint. Zero extra per-iteration ops.
// Carried from R7: 128-thr blocks (2 waves, K-split 32/32), fire-and-forget
// ds_min g2p, key-packing top-2, packed-fp32 dot pairs, x16 replicated
// global atomics, LDS publish + wave-B epilogue, tiny finalize dispatch.

constexpr int KT = 64;
constexpr int P  = 4;
constexpr int NREP = 16;
constexpr float DIST_THRESH = 0.1f;
constexpr float W_DIST    = 0.05f;
constexpr float W_CHAMFER = 0.05f;
constexpr float W_SEP     = 0.0005f;
constexpr float PT_SENT = -1e18f;  // dummy-point sentinel (tail lanes)
constexpr float TG_SENT = -1e18f;  // invalid-target sentinel
constexpr float BIGF  = 3.0e38f;
constexpr float WBIAS = 16.0f;     // |t|^2 + WBIAS in T.w keeps valid keys > 0

typedef float f2 __attribute__((ext_vector_type(2)));

__device__ __forceinline__ unsigned umin_(unsigned a, unsigned b) { return a < b ? a : b; }
__device__ __forceinline__ unsigned umax_(unsigned a, unsigned b) { return a > b ? a : b; }

__device__ __forceinline__ f2 pk_fma(f2 a, f2 b, f2 c) {
#if __has_builtin(__builtin_elementwise_fma)
    return __builtin_elementwise_fma(a, b, c);
#else
    f2 r; r.x = fmaf(a.x, b.x, c.x); r.y = fmaf(a.y, b.y, c.y); return r;
#endif
}

// ws layout: [0,16384) g2p replicas rep*256+b*64+k (encode ~bits(g), init 0);
//            [16384,17408) sums replicas rep*16 + c*4 + b (float, init 0)
__global__ __launch_bounds__(128, 6)
void landmark_main(const float* __restrict__ C, const float* __restrict__ F,
                   const float* __restrict__ tC, const int* __restrict__ tF,
                   const int* __restrict__ classes, int n_classes,
                   int N, unsigned int* __restrict__ g2p_rep,
                   float* __restrict__ sums_rep)
{
    __shared__ float4 tgtH[2][32];     // per-half targets
    __shared__ float4 tgtFull[KT];     // full list for epilogue companion lookups
    __shared__ unsigned g2pLDS[KT];    // per-target min bits (float >= 0)
    __shared__ uint4  mK1[64];         // wave A -> B merge buffers
    __shared__ uint4  mK2[64];
    __shared__ float4 mLM[64];

    const int tid   = threadIdx.x;
    const int lane  = tid & 63;
    const int h     = tid >> 6;        // 0: targets [0,32), 1: [32,64)
    const int l31   = lane & 31;
    const int lx    = l31 ^ ((lane >> 5) << 4);   // de-collide ds_min addresses
    const int blk   = blockIdx.x;
    const int b     = blk & 3;
    const int chunk = blk >> 2;
    const int rep   = chunk & (NREP - 1);
    const unsigned kbase = (unsigned)(h << 5);

    // Stage 64 targets: (-2tx,-2ty,-2tz, |t|^2+WBIAS), sentinel if invalid.
    if (tid < KT) {
        int f = tF[b * KT + tid];
        bool valid = false;
        for (int c = 0; c < n_classes; ++c) valid = valid || (f == classes[c]);
        float x = TG_SENT, y = TG_SENT, z = TG_SENT;
        if (valid) {
            x = tC[(b * KT + tid) * 3 + 0];
            y = tC[(b * KT + tid) * 3 + 1];
            z = tC[(b * KT + tid) * 3 + 2];
        }
        float4 v = make_float4(-2.f * x, -2.f * y, -2.f * z,
                               x * x + y * y + z * z + WBIAS);
        tgtFull[tid] = v;
        tgtH[tid >> 5][tid & 31] = v;
        g2pLDS[tid] = 0x7F7FFFFFu;     // FLT_MAX bits
    }
    __syncthreads();

    const float*  Cb = C + (size_t)b * N * 3;
    const float4* Fb = (const float4*)(F + (size_t)b * N * 4);
    const int base = chunk * (64 * P);

    // ---- stage this chunk's 256 points (both waves load the same points) ----
    f2 pcx[P], pcy[P], pcz[P];         // (raw coord, offset coord) packed pairs
    float ppm[P], ccm[P], f0[P];
    #pragma unroll
    for (int p = 0; p < P; ++p) {
        int n = base + p * 64 + lane;
        bool v = (n < N);
        int ni = v ? n : 0;
        float4 f4 = Fb[ni];
        float X = Cb[3 * ni + 0], Y = Cb[3 * ni + 1], Z = Cb[3 * ni + 2];
        // dummy points: coords -> sentinel; f0 -> 0.2 so dist term cancels.
        f0[p] = v ? f4.x : 2.0f * DIST_THRESH;
        if (!v) { X = PT_SENT; Y = PT_SENT; Z = PT_SENT; f4.y = f4.z = f4.w = 0.f; }
        float cxv = X + f4.y, cyv = Y + f4.z, czv = Z + f4.w;
        pcx[p] = (f2){X, cxv};
        pcy[p] = (f2){Y, cyv};
        pcz[p] = (f2){Z, czv};
        ppm[p] = fmaf(Z, Z, fmaf(Y, Y, X * X)) - WBIAS;
        ccm[p] = fmaf(czv, czv, fmaf(cyv, cyv, cxv * cxv)) - WBIAS;
    }

    // keyf = T.w - 2 p.t (= true pd2 - |p|^2 + WBIAS, > 0 for valid pairs)
    unsigned k1[P], k2[P];
    float lmin[P];
    #pragma unroll
    for (int p = 0; p < P; ++p) { k1[p] = 0xFFFFFFFFu; k2[p] = 0xFFFFFFFFu; lmin[p] = BIGF; }

    #pragma unroll 8
    for (int i = 0; i < 32; ++i) {
        const unsigned kk = (unsigned)(lx ^ i);       // bijection; halves disjoint
        const float4 T = tgtH[h][kk];
        const unsigned tk = kk | kbase;
        const f2 Tx = {T.x, T.x}, Ty = {T.y, T.y}, Tz = {T.z, T.z}, Tw = {T.w, T.w};
        float av[P];
        #pragma unroll
        for (int p = 0; p < P; ++p) {
            f2 w = pk_fma(pcx[p], Tx, pk_fma(pcy[p], Ty, pk_fma(pcz[p], Tz, Tw)));
            unsigned key = (__float_as_uint(w.x) & 0xFFFFFFC0u) | tk;
            unsigned hi = umax_(k1[p], key);
            k1[p] = umin_(k1[p], key);
            k2[p] = umin_(k2[p], hi);
            lmin[p] = fminf(lmin[p], w.y);
            av[p] = w.y + ccm[p];                     // true ld2 for cross-p compare
        }
        float dl = fmaxf(fminf(fminf(av[0], av[1]), fminf(av[2], av[3])), 0.f);
        atomicMin(&g2pLDS[tk], __float_as_uint(dl));  // ds_min_u32, no return
    }

    // ---- wave A publishes its half's per-point state for the merge ----
    if (h == 0) {
        mK1[lane] = make_uint4(k1[0], k1[1], k1[2], k1[3]);
        mK2[lane] = make_uint4(k2[0], k2[1], k2[2], k2[3]);
        mLM[lane] = make_float4(lmin[0], lmin[1], lmin[2], lmin[3]);
    }
    __syncthreads();   // covers ds_min completion + merge publish

    if (h == 0) {
        // per-target g2p -> replicated global (wave A, one lane per target).
        // g2pLDS holds bits(g), g>=0; ~bits monotone decreasing -> atomicMax == min.
        atomicMax(&g2p_rep[rep * 256 + b * 64 + lane], ~g2pLDS[lane]);
    } else {
        // ---- merge halves + epilogue (wave B only) ----
        uint4 A1 = mK1[lane], A2 = mK2[lane];
        float4 AL = mLM[lane];
        const unsigned a1v[P] = {A1.x, A1.y, A1.z, A1.w};
        const unsigned a2v[P] = {A2.x, A2.y, A2.z, A2.w};
        const float    alv[P] = {AL.x, AL.y, AL.z, AL.w};

        float dist_acc = 0.f, p2g_acc = 0.f, sep_acc = 0.f;
        #pragma unroll
        for (int p = 0; p < P; ++p) {
            unsigned m1 = umin_(a1v[p], k1[p]);
            unsigned m2 = umin_(umax_(a1v[p], k1[p]), umin_(a2v[p], k2[p]));
            float lm = fminf(alv[p], lmin[p]);
            float keyf1 = __uint_as_float(m1 & 0xFFFFFFC0u);
            float mind = sqrtf(fmaxf(keyf1 + ppm[p], 0.f));
            bool pm = mind < DIST_THRESH;            // false for dummy (ppm huge)
            float tgtv = fminf(mind, 2.0f * DIST_THRESH);
            float diff = f0[p] - tgtv;
            float ad = fabsf(diff);
            dist_acc += (ad < 1.0f) ? 0.5f * diff * diff : (ad - 0.5f);
            if (pm) {
                p2g_acc += fmaxf(lm + ccm[p], 0.f);
                int i1 = (int)(m1 & 63u), i2 = (int)(m2 & 63u);
                float4 T1 = tgtFull[i1], T2 = tgtFull[i2];
                float cxv = pcx[p].y, cyv = pcy[p].y, czv = pcz[p].y;
                float l1sq = fmaf(cxv, T1.x, fmaf(cyv, T1.y, fmaf(czv, T1.z, T1.w))) + ccm[p];
                float l2sq = fmaf(cxv, T2.x, fmaf(cyv, T2.y, fmaf(czv, T2.z, T2.w))) + ccm[p];
                sep_acc += sqrtf(fmaxf(l1sq, 0.f) / fmaxf(l2sq, 1e-30f));
            }
        }

        float v0 = dist_acc, v1 = p2g_acc, v2 = sep_acc;
        #pragma unroll
        for (int o = 32; o > 0; o >>= 1) {
            v0 += __shfl_down(v0, o, 64);
            v1 += __shfl_down(v1, o, 64);
            v2 += __shfl_down(v2, o, 64);
        }
        if (lane == 0) {
            float* sb = sums_rep + rep * 16 + b;
            atomicAdd(sb + 0, v0);
            atomicAdd(sb + 4, v1);
            atomicAdd(sb + 8, v2);
        }
    }
}

__global__ void landmark_finalize(const int* __restrict__ tF, const int* __restrict__ classes,
                                  int n_classes, const unsigned int* __restrict__ g2p_rep,
                                  const float* __restrict__ sums_rep, float* __restrict__ out)
{
    __shared__ float lossb[4];
    const int tid = threadIdx.x;          // 256 threads
    const int b = tid >> 6, k = tid & 63;

    int f = tF[b * KT + k];
    bool valid = false;
    for (int c = 0; c < n_classes; ++c) valid = valid || (f == classes[c]);

    unsigned enc = 0;
    for (int r = 0; r < NREP; ++r) enc = umax_(enc, g2p_rep[r * 256 + b * 64 + k]);
    float g  = valid ? __uint_as_float(~enc) : 0.f;
    float nv = valid ? 1.f : 0.f;

    #pragma unroll
    for (int o = 32; o > 0; o >>= 1) {
        g  += __shfl_down(g, o, 64);
        nv += __shfl_down(nv, o, 64);
    }
    if (k == 0) {
        float sd = 0.f, sp = 0.f, ss = 0.f;
        for (int r = 0; r < NREP; ++r) {
            sd += sums_rep[r * 16 + 0 + b];
            sp += sums_rep[r * 16 + 4 + b];
            ss += sums_rep[r * 16 + 8 + b];
        }
        float sep = (nv >= 2.f) ? ss : 0.f;
        lossb[b] = W_DIST * sd + W_CHAMFER * (sp + g) + W_SEP * sep;
    }
    __syncthreads();
    if (tid == 0)
        out[0] = (lossb[0] + lossb[1] + lossb[2] + lossb[3]) * 0.25f;
}

extern "C" void kernel_launch(void* const* d_in, const int* in_sizes, int n_in,
                              void* d_out, int out_size, void* d_ws, size_t ws_size,
                              hipStream_t stream)
{
    const float* C       = (const float*)d_in[0];   // (B,N,3)
    const float* F       = (const float*)d_in[1];   // (B,N,4)
    const float* tC      = (const float*)d_in[2];   // (B,K,3)
    const int*   tF      = (const int*)d_in[3];     // (B,K)
    const int*   classes = (const int*)d_in[4];     // (6,)
    const int n_classes = in_sizes[4];
    const int B = 4;
    const int N = in_sizes[0] / (3 * B);            // 200000

    unsigned int* g2p_rep  = (unsigned int*)d_ws;
    float*        sums_rep = (float*)((char*)d_ws + NREP * 256 * 4);

    hipMemsetAsync(d_ws, 0, NREP * 256 * 4 + NREP * 16 * 4, stream);

    const int cpb = (N + 64 * P - 1) / (64 * P);    // 782 chunks per batch
    landmark_main<<<cpb * 4, 128, 0, stream>>>(C, F, tC, tF, classes, n_classes,
                                               N, g2p_rep, sums_rep);
    landmark_finalize<<<1, 256, 0, stream>>>(tF, classes, n_classes, g2p_rep,
                                             sums_rep, (float*)d_out);
}